// Round 7
// baseline (384.113 us; speedup 1.0000x reference)
//
#include <hip/hip_runtime.h>
#include <hip/hip_bf16.h>
#include <stdint.h>

#define D_MODEL 768
#define NH 12
#define DH 64
#define BB 2
#define TT 2048
#define BT (BB*TT)   // 4096 tokens

typedef unsigned short u16;
typedef __attribute__((ext_vector_type(8))) short short8;
typedef __attribute__((ext_vector_type(4))) float f32x4;
typedef __attribute__((ext_vector_type(4))) u16 u16x4;

__device__ __forceinline__ u16 f2bf(float f) {
  union { float f; unsigned int u; } c; c.f = f;
  unsigned int u = c.u;
  u += 0x7fff + ((u >> 16) & 1);   // RNE
  return (u16)(u >> 16);
}

__device__ __forceinline__ float bf2f(u16 b) {
  union { unsigned int u; float f; } c; c.u = ((unsigned int)b) << 16;
  return c.f;
}

__device__ __forceinline__ void gload_lds16(const void* g, void* l) {
  __builtin_amdgcn_global_load_lds(
      (const __attribute__((address_space(1))) void*)g,
      (__attribute__((address_space(3))) void*)l, 16, 0, 0);
}

// ---------------- x -> bf16 (vectorized) ----------------
__global__ void k_convert_x(const float* __restrict__ in, u16* __restrict__ out, int n4) {
  int i = blockIdx.x * blockDim.x + threadIdx.x;
  if (i >= n4) return;
  float4 v = ((const float4*)in)[i];
  unsigned int p0 = (unsigned int)f2bf(v.x) | ((unsigned int)f2bf(v.y) << 16);
  unsigned int p1 = (unsigned int)f2bf(v.z) | ((unsigned int)f2bf(v.w) << 16);
  ((uint2*)out)[i] = make_uint2(p0, p1);
}

// ---------------- W [R][C] f32 -> W^T [C][R] bf16 ----------------
__global__ void k_transpose_bf16(const float* __restrict__ in, u16* __restrict__ out, int R, int C) {
  __shared__ float tile[32][33];
  int bc = blockIdx.x * 32;   // col base
  int br = blockIdx.y * 32;   // row base
  int tx = threadIdx.x, ty = threadIdx.y;   // 32 x 8
  #pragma unroll
  for (int i = 0; i < 32; i += 8)
    tile[ty + i][tx] = in[(size_t)(br + ty + i) * C + bc + tx];
  __syncthreads();
  #pragma unroll
  for (int i = 0; i < 32; i += 8)
    out[(size_t)(bc + ty + i) * R + br + tx] = f2bf(tile[tx][ty + i]);
}

// ---------------- GEMM: [M][K]bf16 x [N][K]bf16^T, 128x128 tile, 4 waves ----------------
template<int MODE>
__global__ __launch_bounds__(256, 2)
void k_gemm(const u16* __restrict__ Abf, const u16* __restrict__ Bt,
            const float* __restrict__ bias0, const float* __restrict__ bias1,
            const float* __restrict__ bias2,
            u16* __restrict__ q_buf, u16* __restrict__ k_buf, u16* __restrict__ vt_buf,
            float* __restrict__ out, int K) {
  __shared__ u16 As[128 * 32];
  __shared__ u16 Bs[128 * 32];
  int tid = threadIdx.x;
  int lane = tid & 63, w = tid >> 6;
  int ln = lane & 15, lg = lane >> 4;
  int wm = w >> 1, wn = w & 1;
  int m0 = blockIdx.y * 128, n0 = blockIdx.x * 128;
  f32x4 acc[4][4] = {};
  int c0 = tid, c1 = tid + 256;

  for (int kb = 0; kb < K; kb += 32) {
    gload_lds16(Abf + (size_t)(m0 + (c0 >> 2)) * K + kb + (c0 & 3) * 8, (char*)As + c0 * 16);
    gload_lds16(Abf + (size_t)(m0 + (c1 >> 2)) * K + kb + (c1 & 3) * 8, (char*)As + c1 * 16);
    gload_lds16(Bt  + (size_t)(n0 + (c0 >> 2)) * K + kb + (c0 & 3) * 8, (char*)Bs + c0 * 16);
    gload_lds16(Bt  + (size_t)(n0 + (c1 >> 2)) * K + kb + (c1 & 3) * 8, (char*)Bs + c1 * 16);
    __syncthreads();
    short8 af[4], bfr[4];
    #pragma unroll
    for (int mt = 0; mt < 4; ++mt)
      af[mt] = *(const short8*)&As[(wm * 64 + mt * 16 + ln) * 32 + lg * 8];
    #pragma unroll
    for (int nt = 0; nt < 4; ++nt)
      bfr[nt] = *(const short8*)&Bs[(wn * 64 + nt * 16 + ln) * 32 + lg * 8];
    #pragma unroll
    for (int mt = 0; mt < 4; ++mt)
      #pragma unroll
      for (int nt = 0; nt < 4; ++nt)
        acc[mt][nt] = __builtin_amdgcn_mfma_f32_16x16x32_bf16(af[mt], bfr[nt], acc[mt][nt], 0, 0, 0);
    __syncthreads();
  }

  #pragma unroll
  for (int mt = 0; mt < 4; ++mt) {
    #pragma unroll
    for (int nt = 0; nt < 4; ++nt) {
      #pragma unroll
      for (int r = 0; r < 4; ++r) {
        int row = m0 + wm * 64 + mt * 16 + lg * 4 + r;   // token index
        int col = n0 + wn * 64 + nt * 16 + ln;
        float v = acc[mt][nt][r];
        if (MODE == 0) {
          int b = row >> 11, t = row & 2047;
          if (col < 768) {
            v += bias0[col];
            int h = col >> 6, d = col & 63;
            q_buf[(((size_t)b * NH + h) * TT + t) * DH + d] = f2bf(v);
          } else if (col < 1536) {
            int c2 = col - 768; v += bias1[c2];
            int h = c2 >> 6, d = c2 & 63;
            k_buf[(((size_t)b * NH + h) * TT + t) * DH + d] = f2bf(v);
          } else {
            int c2 = col - 1536; v += bias2[c2];
            int h = c2 >> 6, d = c2 & 63;
            vt_buf[(((size_t)b * NH + h) * DH + d) * TT + t] = f2bf(v);   // V transposed
          }
        } else {
          out[(size_t)row * 768 + col] = v + bias0[col];
        }
      }
    }
  }
}

// ---------------- (a) k_attn_z: QK^T + exp2 + row-sum + PV -> z, scale ----------------
// One wave = 16 q-rows x all 2048 keys. Stores only at kernel end (decoupled).
__global__ __launch_bounds__(256, 3)
void k_attn_z(const u16* __restrict__ Q, const u16* __restrict__ Kb,
              const u16* __restrict__ Vt, const float* __restrict__ gates,
              float* __restrict__ scale_ws, u16* __restrict__ z_buf) {
  // XCD swizzle: 768 blocks; XCD = flat%8; bh constant per XCD group.
  int flat = blockIdx.x;
  int g = flat & 7, t = flat >> 3;          // t in 0..95
  int qb = t & 31, bh = (t >> 5) * 8 + g;   // bh in 0..23
  int b = bh / NH, h = bh % NH;
  int tid = threadIdx.x;
  int lane = tid & 63, w = tid >> 6;
  int ln = lane & 15, lg = lane >> 4;
  int q0 = qb * 64 + w * 16;
  const u16* Qbh = Q  + (size_t)bh * TT * DH;
  const u16* Kbh = Kb + (size_t)bh * TT * DH;
  const u16* Vbh = Vt + (size_t)bh * DH * TT;
  float gate = gates[bh];

  __shared__ u16 p16[4][16][136];
  const float cs = 0.18033688011112042f;   // log2(e)/sqrt(64)

  short8 qf0 = *(const short8*)&Qbh[(size_t)(q0 + ln) * DH + lg * 8];
  short8 qf1 = *(const short8*)&Qbh[(size_t)(q0 + ln) * DH + 32 + lg * 8];

  f32x4 zacc[4] = {};
  float l[4] = {0.f, 0.f, 0.f, 0.f};

  for (int ch = 0; ch < 16; ++ch) {        // 128-key chunks
    #pragma unroll
    for (int sub = 0; sub < 2; ++sub) {    // 64-key batches
      short8 kt[4][2];
      #pragma unroll
      for (int tt = 0; tt < 4; ++tt) {
        const u16* kp = &Kbh[(size_t)(ch * 128 + sub * 64 + tt * 16 + ln) * DH + lg * 8];
        kt[tt][0] = *(const short8*)kp;
        kt[tt][1] = *(const short8*)(kp + 32);
      }
      __builtin_amdgcn_sched_barrier(0);   // pin: all 8 loads issued before compute
      #pragma unroll
      for (int tt = 0; tt < 4; ++tt) {
        f32x4 c = {0.f, 0.f, 0.f, 0.f};
        c = __builtin_amdgcn_mfma_f32_16x16x32_bf16(qf0, kt[tt][0], c, 0, 0, 0);
        c = __builtin_amdgcn_mfma_f32_16x16x32_bf16(qf1, kt[tt][1], c, 0, 0, 0);
        #pragma unroll
        for (int r = 0; r < 4; ++r) {
          float e = __builtin_amdgcn_exp2f(c[r] * cs);
          l[r] += e;
          p16[w][lg * 4 + r][sub * 64 + tt * 16 + ln] = f2bf(e);
        }
      }
    }
    // PV over this 128-key chunk
    #pragma unroll
    for (int ks = 0; ks < 4; ++ks) {
      short8 pf = *(const short8*)&p16[w][ln][ks * 32 + lg * 8];
      short8 vt_[4];
      #pragma unroll
      for (int dt = 0; dt < 4; ++dt)
        vt_[dt] = *(const short8*)&Vbh[(size_t)(dt * 16 + ln) * TT + ch * 128 + ks * 32 + lg * 8];
      __builtin_amdgcn_sched_barrier(0);
      #pragma unroll
      for (int dt = 0; dt < 4; ++dt)
        zacc[dt] = __builtin_amdgcn_mfma_f32_16x16x32_bf16(pf, vt_[dt], zacc[dt], 0, 0, 0);
    }
  }

  // wave-internal row-sum reduce (16-lane key groups)
  #pragma unroll
  for (int r = 0; r < 4; ++r)
    #pragma unroll
    for (int mk = 1; mk <= 8; mk <<= 1) l[r] += __shfl_xor(l[r], mk, 64);
  float scale[4];
  #pragma unroll
  for (int r = 0; r < 4; ++r) scale[r] = gate / l[r];

  if (ln == 0) {
    #pragma unroll
    for (int r = 0; r < 4; ++r)
      scale_ws[(size_t)bh * TT + q0 + lg * 4 + r] = scale[r];
  }

  #pragma unroll
  for (int dt = 0; dt < 4; ++dt)
    #pragma unroll
    for (int r = 0; r < 4; ++r)
      z_buf[((size_t)b * TT + q0 + lg * 4 + r) * D_MODEL + h * DH + dt * 16 + ln] =
          f2bf(zacc[dt][r] * scale[r]);
}

// ---------------- (b) k_awrite v2: compute-all-then-store-all ----------------
// Block = 4 waves x 16 q-rows; wave w computes keys [w*512,(w+1)*512) into LDS
// bf16 (final gated-normalized A), then a PURE store burst: 1KB contiguous
// dwordx4 stores, no load-waits interleaved (stores never block compute).
__global__ __launch_bounds__(256, 2)
void k_awrite(const u16* __restrict__ Q, const u16* __restrict__ Kb,
              const float* __restrict__ scale_ws, float* __restrict__ A_out) {
  int flat = blockIdx.x;
  int g = flat & 7, t = flat >> 3;            // t in 0..383
  int qt = t & 127, bh = (t >> 7) * 8 + g;    // bh in 0..23
  int tid = threadIdx.x;
  int lane = tid & 63, w = tid >> 6;
  int ln = lane & 15, lg = lane >> 4;
  int q0 = qt * 16;
  const u16* Qbh = Q  + (size_t)bh * TT * DH;
  const u16* Kbh = Kb + (size_t)bh * TT * DH;

  __shared__ u16 pa[4][16][520];   // 66.6 KB: full 16x512 bf16 A-tile per wave
  const float cs = 0.18033688011112042f;

  short8 qf0 = *(const short8*)&Qbh[(size_t)(q0 + ln) * DH + lg * 8];
  short8 qf1 = *(const short8*)&Qbh[(size_t)(q0 + ln) * DH + 32 + lg * 8];

  float scale[4];
  #pragma unroll
  for (int r = 0; r < 4; ++r)
    scale[r] = scale_ws[(size_t)bh * TT + q0 + lg * 4 + r];

  int kb0 = w * 512;

  // ---- compute phase: loads + MFMA + exp2 only ----
  for (int sub = 0; sub < 8; ++sub) {       // 64-key subchunks
    short8 kt[4][2];
    #pragma unroll
    for (int tt = 0; tt < 4; ++tt) {
      const u16* kp = &Kbh[(size_t)(kb0 + sub * 64 + tt * 16 + ln) * DH + lg * 8];
      kt[tt][0] = *(const short8*)kp;
      kt[tt][1] = *(const short8*)(kp + 32);
    }
    __builtin_amdgcn_sched_barrier(0);
    #pragma unroll
    for (int tt = 0; tt < 4; ++tt) {
      f32x4 c = {0.f, 0.f, 0.f, 0.f};
      c = __builtin_amdgcn_mfma_f32_16x16x32_bf16(qf0, kt[tt][0], c, 0, 0, 0);
      c = __builtin_amdgcn_mfma_f32_16x16x32_bf16(qf1, kt[tt][1], c, 0, 0, 0);
      #pragma unroll
      for (int r = 0; r < 4; ++r)
        pa[w][lg * 4 + r][sub * 64 + tt * 16 + ln] =
            f2bf(__builtin_amdgcn_exp2f(c[r] * cs) * scale[r]);
    }
  }

  // ---- store phase: pure burst, 1KB contiguous per instruction ----
  float* Arow = A_out + ((size_t)bh * TT + q0) * TT;
  #pragma unroll
  for (int row = 0; row < 16; ++row) {
    #pragma unroll
    for (int hf = 0; hf < 2; ++hf) {        // two 256-f32 halves of the 512-key span
      u16x4 pk = *(const u16x4*)&pa[w][row][hf * 256 + lane * 4];
      f32x4 v;
      v.x = bf2f(pk.x); v.y = bf2f(pk.y); v.z = bf2f(pk.z); v.w = bf2f(pk.w);
      *(f32x4*)&Arow[(size_t)row * TT + kb0 + hf * 256 + lane * 4] = v;
    }
  }
}

extern "C" void kernel_launch(void* const* d_in, const int* in_sizes, int n_in,
                              void* d_out, int out_size, void* d_ws, size_t ws_size,
                              hipStream_t stream) {
  const float* x     = (const float*)d_in[0];
  const float* gates = (const float*)d_in[1];
  const float* Wq    = (const float*)d_in[2];
  const float* bq    = (const float*)d_in[3];
  const float* Wk    = (const float*)d_in[4];
  const float* bk    = (const float*)d_in[5];
  const float* Wv    = (const float*)d_in[6];
  const float* bv    = (const float*)d_in[7];
  const float* Wo    = (const float*)d_in[8];
  const float* bo    = (const float*)d_in[9];
  float* out   = (float*)d_out;
  float* A_out = out + (size_t)BT * D_MODEL;

  char* ws = (char*)d_ws;
  u16* x_bf   = (u16*)ws; ws += (size_t)BT * D_MODEL * 2;
  u16* wqkvT  = (u16*)ws; ws += (size_t)3 * D_MODEL * D_MODEL * 2;
  u16* woT    = (u16*)ws; ws += (size_t)D_MODEL * D_MODEL * 2;
  u16* q_buf  = (u16*)ws; ws += (size_t)BT * D_MODEL * 2;
  u16* k_buf  = (u16*)ws; ws += (size_t)BT * D_MODEL * 2;
  u16* vt_buf = (u16*)ws; ws += (size_t)BT * D_MODEL * 2;
  u16* z_buf  = (u16*)ws; ws += (size_t)BT * D_MODEL * 2;
  float* scale_ws = (float*)ws; ws += (size_t)BB * NH * TT * 4;

  k_convert_x<<<(BT * D_MODEL / 4 + 255) / 256, 256, 0, stream>>>(x, x_bf, BT * D_MODEL / 4);
  dim3 tb(32, 8);
  dim3 tg(D_MODEL / 32, D_MODEL / 32);
  k_transpose_bf16<<<tg, tb, 0, stream>>>(Wq, wqkvT, D_MODEL, D_MODEL);
  k_transpose_bf16<<<tg, tb, 0, stream>>>(Wk, wqkvT + (size_t)D_MODEL * D_MODEL, D_MODEL, D_MODEL);
  k_transpose_bf16<<<tg, tb, 0, stream>>>(Wv, wqkvT + (size_t)2 * D_MODEL * D_MODEL, D_MODEL, D_MODEL);
  k_transpose_bf16<<<tg, tb, 0, stream>>>(Wo, woT, D_MODEL, D_MODEL);

  k_gemm<0><<<dim3(2304 / 128, BT / 128), 256, 0, stream>>>(
      x_bf, wqkvT, bq, bk, bv, q_buf, k_buf, vt_buf, nullptr, D_MODEL);

  k_attn_z<<<dim3(768), 256, 0, stream>>>(q_buf, k_buf, vt_buf, gates, scale_ws, z_buf);
  k_awrite<<<dim3(3072), 256, 0, stream>>>(q_buf, k_buf, scale_ws, A_out);

  k_gemm<1><<<dim3(D_MODEL / 128, BT / 128), 256, 0, stream>>>(
      z_buf, woT, bo, nullptr, nullptr, nullptr, nullptr, nullptr, out, D_MODEL);
}

// Round 13
// 380.193 us; speedup vs baseline: 1.0103x; 1.0103x over previous
//
#include <hip/hip_runtime.h>
#include <hip/hip_bf16.h>
#include <stdint.h>

#define D_MODEL 768
#define NH 12
#define DH 64
#define BB 2
#define TT 2048
#define BT (BB*TT)   // 4096 tokens

typedef unsigned short u16;
typedef __attribute__((ext_vector_type(8))) short short8;
typedef __attribute__((ext_vector_type(4))) float f32x4;
typedef __attribute__((ext_vector_type(4))) u16 u16x4;

__device__ __forceinline__ u16 f2bf(float f) {
  union { float f; unsigned int u; } c; c.f = f;
  unsigned int u = c.u;
  u += 0x7fff + ((u >> 16) & 1);   // RNE
  return (u16)(u >> 16);
}

__device__ __forceinline__ float bf2f_hi(unsigned int packed_hi) {
  union { unsigned int u; float f; } c; c.u = packed_hi;
  return c.f;
}

__device__ __forceinline__ void gload_lds16(const void* g, void* l) {
  __builtin_amdgcn_global_load_lds(
      (const __attribute__((address_space(1))) void*)g,
      (__attribute__((address_space(3))) void*)l, 16, 0, 0);
}

// ---------------- x -> bf16 (vectorized) ----------------
__global__ void k_convert_x(const float* __restrict__ in, u16* __restrict__ out, int n4) {
  int i = blockIdx.x * blockDim.x + threadIdx.x;
  if (i >= n4) return;
  float4 v = ((const float4*)in)[i];
  unsigned int p0 = (unsigned int)f2bf(v.x) | ((unsigned int)f2bf(v.y) << 16);
  unsigned int p1 = (unsigned int)f2bf(v.z) | ((unsigned int)f2bf(v.w) << 16);
  ((uint2*)out)[i] = make_uint2(p0, p1);
}

// ---------------- W [R][C] f32 -> W^T [C][R] bf16 ----------------
__global__ void k_transpose_bf16(const float* __restrict__ in, u16* __restrict__ out, int R, int C) {
  __shared__ float tile[32][33];
  int bc = blockIdx.x * 32;
  int br = blockIdx.y * 32;
  int tx = threadIdx.x, ty = threadIdx.y;   // 32 x 8
  #pragma unroll
  for (int i = 0; i < 32; i += 8)
    tile[ty + i][tx] = in[(size_t)(br + ty + i) * C + bc + tx];
  __syncthreads();
  #pragma unroll
  for (int i = 0; i < 32; i += 8)
    out[(size_t)(bc + ty + i) * R + br + tx] = f2bf(tile[tx][ty + i]);
}

// ---------------- GEMM: [M][K]bf16 x [N][K]bf16^T, 128x128 tile, 4 waves ----------------
template<int MODE>
__global__ __launch_bounds__(256, 2)
void k_gemm(const u16* __restrict__ Abf, const u16* __restrict__ Bt,
            const float* __restrict__ bias0, const float* __restrict__ bias1,
            const float* __restrict__ bias2,
            u16* __restrict__ q_buf, u16* __restrict__ k_buf, u16* __restrict__ vt_buf,
            float* __restrict__ out, int K) {
  __shared__ u16 As[128 * 32];
  __shared__ u16 Bs[128 * 32];
  int tid = threadIdx.x;
  int lane = tid & 63, w = tid >> 6;
  int ln = lane & 15, lg = lane >> 4;
  int wm = w >> 1, wn = w & 1;
  int m0 = blockIdx.y * 128, n0 = blockIdx.x * 128;
  f32x4 acc[4][4] = {};
  int c0 = tid, c1 = tid + 256;

  for (int kb = 0; kb < K; kb += 32) {
    gload_lds16(Abf + (size_t)(m0 + (c0 >> 2)) * K + kb + (c0 & 3) * 8, (char*)As + c0 * 16);
    gload_lds16(Abf + (size_t)(m0 + (c1 >> 2)) * K + kb + (c1 & 3) * 8, (char*)As + c1 * 16);
    gload_lds16(Bt  + (size_t)(n0 + (c0 >> 2)) * K + kb + (c0 & 3) * 8, (char*)Bs + c0 * 16);
    gload_lds16(Bt  + (size_t)(n0 + (c1 >> 2)) * K + kb + (c1 & 3) * 8, (char*)Bs + c1 * 16);
    __syncthreads();
    short8 af[4], bfr[4];
    #pragma unroll
    for (int mt = 0; mt < 4; ++mt)
      af[mt] = *(const short8*)&As[(wm * 64 + mt * 16 + ln) * 32 + lg * 8];
    #pragma unroll
    for (int nt = 0; nt < 4; ++nt)
      bfr[nt] = *(const short8*)&Bs[(wn * 64 + nt * 16 + ln) * 32 + lg * 8];
    #pragma unroll
    for (int mt = 0; mt < 4; ++mt)
      #pragma unroll
      for (int nt = 0; nt < 4; ++nt)
        acc[mt][nt] = __builtin_amdgcn_mfma_f32_16x16x32_bf16(af[mt], bfr[nt], acc[mt][nt], 0, 0, 0);
    __syncthreads();
  }

  #pragma unroll
  for (int mt = 0; mt < 4; ++mt) {
    #pragma unroll
    for (int nt = 0; nt < 4; ++nt) {
      #pragma unroll
      for (int r = 0; r < 4; ++r) {
        int row = m0 + wm * 64 + mt * 16 + lg * 4 + r;
        int col = n0 + wn * 64 + nt * 16 + ln;
        float v = acc[mt][nt][r];
        if (MODE == 0) {
          int b = row >> 11, t = row & 2047;
          if (col < 768) {
            v += bias0[col];
            int h = col >> 6, d = col & 63;
            q_buf[(((size_t)b * NH + h) * TT + t) * DH + d] = f2bf(v);
          } else if (col < 1536) {
            int c2 = col - 768; v += bias1[c2];
            int h = c2 >> 6, d = c2 & 63;
            k_buf[(((size_t)b * NH + h) * TT + t) * DH + d] = f2bf(v);
          } else {
            int c2 = col - 1536; v += bias2[c2];
            int h = c2 >> 6, d = c2 & 63;
            vt_buf[(((size_t)b * NH + h) * DH + d) * TT + t] = f2bf(v);   // V transposed
          }
        } else {
          out[(size_t)row * 768 + col] = v + bias0[col];
        }
      }
    }
  }
}

// ---------------- k_attn_z: QK^T + exp2 + row-sum + PV -> z, scale, P-bf16 ----------------
// One wave = 16 q-rows x all 2048 keys (R6-proven structure). Additionally dumps
// the unnormalized P tile (bf16) to pbuf for the streaming A-expander.
__global__ __launch_bounds__(256, 3)
void k_attn_z(const u16* __restrict__ Q, const u16* __restrict__ Kb,
              const u16* __restrict__ Vt, const float* __restrict__ gates,
              float* __restrict__ scale_ws, u16* __restrict__ z_buf,
              u16* __restrict__ pbuf) {
  // XCD swizzle: 768 blocks; XCD = flat%8; bh constant per XCD group.
  int flat = blockIdx.x;
  int g = flat & 7, t = flat >> 3;          // t in 0..95
  int qb = t & 31, bh = (t >> 5) * 8 + g;   // bh in 0..23
  int b = bh / NH, h = bh % NH;
  int tid = threadIdx.x;
  int lane = tid & 63, w = tid >> 6;
  int ln = lane & 15, lg = lane >> 4;
  int q0 = qb * 64 + w * 16;
  const u16* Qbh = Q  + (size_t)bh * TT * DH;
  const u16* Kbh = Kb + (size_t)bh * TT * DH;
  const u16* Vbh = Vt + (size_t)bh * DH * TT;
  float gate = gates[bh];

  __shared__ u16 p16[4][16][136];
  const float cs = 0.18033688011112042f;   // log2(e)/sqrt(64)

  short8 qf0 = *(const short8*)&Qbh[(size_t)(q0 + ln) * DH + lg * 8];
  short8 qf1 = *(const short8*)&Qbh[(size_t)(q0 + ln) * DH + 32 + lg * 8];

  f32x4 zacc[4] = {};
  float l[4] = {0.f, 0.f, 0.f, 0.f};
  u16* Ptile = pbuf + ((size_t)bh * TT + q0) * TT;

  for (int ch = 0; ch < 16; ++ch) {        // 128-key chunks
    #pragma unroll
    for (int sub = 0; sub < 2; ++sub) {    // 64-key batches
      short8 kt[4][2];
      #pragma unroll
      for (int tt = 0; tt < 4; ++tt) {
        const u16* kp = &Kbh[(size_t)(ch * 128 + sub * 64 + tt * 16 + ln) * DH + lg * 8];
        kt[tt][0] = *(const short8*)kp;
        kt[tt][1] = *(const short8*)(kp + 32);
      }
      __builtin_amdgcn_sched_barrier(0);   // pin: all 8 loads issued before compute
      #pragma unroll
      for (int tt = 0; tt < 4; ++tt) {
        f32x4 c = {0.f, 0.f, 0.f, 0.f};
        c = __builtin_amdgcn_mfma_f32_16x16x32_bf16(qf0, kt[tt][0], c, 0, 0, 0);
        c = __builtin_amdgcn_mfma_f32_16x16x32_bf16(qf1, kt[tt][1], c, 0, 0, 0);
        #pragma unroll
        for (int r = 0; r < 4; ++r) {
          float e = __builtin_amdgcn_exp2f(c[r] * cs);
          l[r] += e;
          p16[w][lg * 4 + r][sub * 64 + tt * 16 + ln] = f2bf(e);
        }
      }
    }
    // PV over this 128-key chunk
    #pragma unroll
    for (int ks = 0; ks < 4; ++ks) {
      short8 pf = *(const short8*)&p16[w][ln][ks * 32 + lg * 8];
      short8 vt_[4];
      #pragma unroll
      for (int dt = 0; dt < 4; ++dt)
        vt_[dt] = *(const short8*)&Vbh[(size_t)(dt * 16 + ln) * TT + ch * 128 + ks * 32 + lg * 8];
      __builtin_amdgcn_sched_barrier(0);
      #pragma unroll
      for (int dt = 0; dt < 4; ++dt)
        zacc[dt] = __builtin_amdgcn_mfma_f32_16x16x32_bf16(pf, vt_[dt], zacc[dt], 0, 0, 0);
    }
    // P-bf16 writeout: full [16][128] tile = 4096B; 4 iters x 64 lanes x 16B
    #pragma unroll
    for (int i = 0; i < 4; ++i) {
      int f = i * 512 + lane * 8;          // flat u16 idx within the tile
      int row = f >> 7, col = f & 127;
      *(short8*)&Ptile[(size_t)row * TT + ch * 128 + col] =
          *(const short8*)&p16[w][row][col];
    }
  }

  // wave-internal row-sum reduce (16-lane key groups)
  #pragma unroll
  for (int r = 0; r < 4; ++r)
    #pragma unroll
    for (int mk = 1; mk <= 8; mk <<= 1) l[r] += __shfl_xor(l[r], mk, 64);
  float scale[4];
  #pragma unroll
  for (int r = 0; r < 4; ++r) scale[r] = gate / l[r];

  if (ln == 0) {
    #pragma unroll
    for (int r = 0; r < 4; ++r)
      scale_ws[(size_t)bh * TT + q0 + lg * 4 + r] = scale[r];
  }

  #pragma unroll
  for (int dt = 0; dt < 4; ++dt)
    #pragma unroll
    for (int r = 0; r < 4; ++r)
      z_buf[((size_t)b * TT + q0 + lg * 4 + r) * D_MODEL + h * DH + dt * 16 + ln] =
          f2bf(zacc[dt][r] * scale[r]);
}

// ---------------- k_aexpand: pure-stream P-bf16 -> A-f32 (fill-shaped) ----------------
// One thread: read uint4 (8 bf16), apply per-row scale, write two f32x4.
__global__ void k_aexpand(const u16* __restrict__ pbuf,
                          const float* __restrict__ scale_ws,
                          float* __restrict__ A_out) {
  size_t i = (size_t)blockIdx.x * 256 + threadIdx.x;   // uint4 index
  uint4 pv = ((const uint4*)pbuf)[i];
  float sc = scale_ws[(i * 8) >> 11];                  // global q-row index
  f32x4 lo, hi;
  lo.x = bf2f_hi(pv.x << 16) * sc;  lo.y = bf2f_hi(pv.x & 0xffff0000u) * sc;
  lo.z = bf2f_hi(pv.y << 16) * sc;  lo.w = bf2f_hi(pv.y & 0xffff0000u) * sc;
  hi.x = bf2f_hi(pv.z << 16) * sc;  hi.y = bf2f_hi(pv.z & 0xffff0000u) * sc;
  hi.z = bf2f_hi(pv.w << 16) * sc;  hi.w = bf2f_hi(pv.w & 0xffff0000u) * sc;
  ((f32x4*)A_out)[i * 2]     = lo;
  ((f32x4*)A_out)[i * 2 + 1] = hi;
}

extern "C" void kernel_launch(void* const* d_in, const int* in_sizes, int n_in,
                              void* d_out, int out_size, void* d_ws, size_t ws_size,
                              hipStream_t stream) {
  const float* x     = (const float*)d_in[0];
  const float* gates = (const float*)d_in[1];
  const float* Wq    = (const float*)d_in[2];
  const float* bq    = (const float*)d_in[3];
  const float* Wk    = (const float*)d_in[4];
  const float* bk    = (const float*)d_in[5];
  const float* Wv    = (const float*)d_in[6];
  const float* bv    = (const float*)d_in[7];
  const float* Wo    = (const float*)d_in[8];
  const float* bo    = (const float*)d_in[9];
  float* out   = (float*)d_out;
  float* A_out = out + (size_t)BT * D_MODEL;

  char* ws = (char*)d_ws;
  u16* x_bf   = (u16*)ws; ws += (size_t)BT * D_MODEL * 2;
  u16* wqkvT  = (u16*)ws; ws += (size_t)3 * D_MODEL * D_MODEL * 2;
  u16* woT    = (u16*)ws; ws += (size_t)D_MODEL * D_MODEL * 2;
  u16* q_buf  = (u16*)ws; ws += (size_t)BT * D_MODEL * 2;
  u16* k_buf  = (u16*)ws; ws += (size_t)BT * D_MODEL * 2;
  u16* vt_buf = (u16*)ws; ws += (size_t)BT * D_MODEL * 2;
  u16* z_buf  = (u16*)ws; ws += (size_t)BT * D_MODEL * 2;
  float* scale_ws = (float*)ws; ws += (size_t)BB * NH * TT * 4;
  u16* pbuf   = (u16*)ws; ws += (size_t)BB * NH * TT * TT * 2;   // 201 MB

  k_convert_x<<<(BT * D_MODEL / 4 + 255) / 256, 256, 0, stream>>>(x, x_bf, BT * D_MODEL / 4);
  dim3 tb(32, 8);
  dim3 tg(D_MODEL / 32, D_MODEL / 32);
  k_transpose_bf16<<<tg, tb, 0, stream>>>(Wq, wqkvT, D_MODEL, D_MODEL);
  k_transpose_bf16<<<tg, tb, 0, stream>>>(Wk, wqkvT + (size_t)D_MODEL * D_MODEL, D_MODEL, D_MODEL);
  k_transpose_bf16<<<tg, tb, 0, stream>>>(Wv, wqkvT + (size_t)2 * D_MODEL * D_MODEL, D_MODEL, D_MODEL);
  k_transpose_bf16<<<tg, tb, 0, stream>>>(Wo, woT, D_MODEL, D_MODEL);

  k_gemm<0><<<dim3(2304 / 128, BT / 128), 256, 0, stream>>>(
      x_bf, wqkvT, bq, bk, bv, q_buf, k_buf, vt_buf, nullptr, D_MODEL);

  k_attn_z<<<dim3(768), 256, 0, stream>>>(q_buf, k_buf, vt_buf, gates, scale_ws, z_buf, pbuf);

  // A = P * scale, pure stream: 24*2048*2048 bf16 / 8 per thread
  k_aexpand<<<dim3((int)(((size_t)BB * NH * TT * TT / 8) / 256)), 256, 0, stream>>>(
      pbuf, scale_ws, A_out);

  k_gemm<1><<<dim3(D_MODEL / 128, BT / 128), 256, 0, stream>>>(
      z_buf, woT, bo, nullptr, nullptr, nullptr, nullptr, nullptr, out, D_MODEL);
}

// Round 14
// 274.933 us; speedup vs baseline: 1.3971x; 1.3829x over previous
//
#include <hip/hip_runtime.h>
#include <hip/hip_bf16.h>
#include <stdint.h>

#define D_MODEL 768
#define NH 12
#define DH 64
#define BB 2
#define TT 2048
#define BT (BB*TT)   // 4096 tokens
#define NW 8         // waves per attn block

typedef unsigned short u16;
typedef __attribute__((ext_vector_type(8))) short short8;
typedef __attribute__((ext_vector_type(4))) float f32x4;
typedef __attribute__((ext_vector_type(2))) float f32x2;
typedef __attribute__((ext_vector_type(2))) __fp16 half2v;

__device__ __forceinline__ u16 f2bf(float f) {
  union { float f; unsigned int u; } c; c.f = f;
  unsigned int u = c.u;
  u += 0x7fff + ((u >> 16) & 1);   // RNE
  return (u16)(u >> 16);
}

__device__ __forceinline__ float bf2f(u16 b) {
  union { unsigned int u; float f; } c; c.u = ((unsigned int)b) << 16;
  return c.f;
}

__device__ __forceinline__ void gload_lds16(const void* g, void* l) {
  __builtin_amdgcn_global_load_lds(
      (const __attribute__((address_space(1))) void*)g,
      (__attribute__((address_space(3))) void*)l, 16, 0, 0);
}

// ---------------- x -> bf16 (vectorized) ----------------
__global__ void k_convert_x(const float* __restrict__ in, u16* __restrict__ out, int n4) {
  int i = blockIdx.x * blockDim.x + threadIdx.x;
  if (i >= n4) return;
  float4 v = ((const float4*)in)[i];
  unsigned int p0 = (unsigned int)f2bf(v.x) | ((unsigned int)f2bf(v.y) << 16);
  unsigned int p1 = (unsigned int)f2bf(v.z) | ((unsigned int)f2bf(v.w) << 16);
  ((uint2*)out)[i] = make_uint2(p0, p1);
}

// ---------------- W [R][C] f32 -> W^T [C][R] bf16 ----------------
__global__ void k_transpose_bf16(const float* __restrict__ in, u16* __restrict__ out, int R, int C) {
  __shared__ float tile[32][33];
  int bc = blockIdx.x * 32;
  int br = blockIdx.y * 32;
  int tx = threadIdx.x, ty = threadIdx.y;   // 32 x 8
  #pragma unroll
  for (int i = 0; i < 32; i += 8)
    tile[ty + i][tx] = in[(size_t)(br + ty + i) * C + bc + tx];
  __syncthreads();
  #pragma unroll
  for (int i = 0; i < 32; i += 8)
    out[(size_t)(bc + ty + i) * R + br + tx] = f2bf(tile[tx][ty + i]);
}

// ---------------- GEMM: [M][K]bf16 x [N][K]bf16^T, 128x128 tile, 4 waves ----------------
template<int MODE>
__global__ __launch_bounds__(256, 2)
void k_gemm(const u16* __restrict__ Abf, const u16* __restrict__ Bt,
            const float* __restrict__ bias0, const float* __restrict__ bias1,
            const float* __restrict__ bias2,
            u16* __restrict__ q_buf, u16* __restrict__ k_buf, u16* __restrict__ vt_buf,
            float* __restrict__ out, int K) {
  __shared__ u16 As[128 * 32];
  __shared__ u16 Bs[128 * 32];
  int tid = threadIdx.x;
  int lane = tid & 63, w = tid >> 6;
  int ln = lane & 15, lg = lane >> 4;
  int wm = w >> 1, wn = w & 1;
  int m0 = blockIdx.y * 128, n0 = blockIdx.x * 128;
  f32x4 acc[4][4] = {};
  int c0 = tid, c1 = tid + 256;

  for (int kb = 0; kb < K; kb += 32) {
    gload_lds16(Abf + (size_t)(m0 + (c0 >> 2)) * K + kb + (c0 & 3) * 8, (char*)As + c0 * 16);
    gload_lds16(Abf + (size_t)(m0 + (c1 >> 2)) * K + kb + (c1 & 3) * 8, (char*)As + c1 * 16);
    gload_lds16(Bt  + (size_t)(n0 + (c0 >> 2)) * K + kb + (c0 & 3) * 8, (char*)Bs + c0 * 16);
    gload_lds16(Bt  + (size_t)(n0 + (c1 >> 2)) * K + kb + (c1 & 3) * 8, (char*)Bs + c1 * 16);
    __syncthreads();
    short8 af[4], bfr[4];
    #pragma unroll
    for (int mt = 0; mt < 4; ++mt)
      af[mt] = *(const short8*)&As[(wm * 64 + mt * 16 + ln) * 32 + lg * 8];
    #pragma unroll
    for (int nt = 0; nt < 4; ++nt)
      bfr[nt] = *(const short8*)&Bs[(wn * 64 + nt * 16 + ln) * 32 + lg * 8];
    #pragma unroll
    for (int mt = 0; mt < 4; ++mt)
      #pragma unroll
      for (int nt = 0; nt < 4; ++nt)
        acc[mt][nt] = __builtin_amdgcn_mfma_f32_16x16x32_bf16(af[mt], bfr[nt], acc[mt][nt], 0, 0, 0);
    __syncthreads();
  }

  #pragma unroll
  for (int mt = 0; mt < 4; ++mt) {
    #pragma unroll
    for (int nt = 0; nt < 4; ++nt) {
      #pragma unroll
      for (int r = 0; r < 4; ++r) {
        int row = m0 + wm * 64 + mt * 16 + lg * 4 + r;
        int col = n0 + wn * 64 + nt * 16 + ln;
        float v = acc[mt][nt][r];
        if (MODE == 0) {
          int b = row >> 11, t = row & 2047;
          if (col < 768) {
            v += bias0[col];
            int h = col >> 6, d = col & 63;
            q_buf[(((size_t)b * NH + h) * TT + t) * DH + d] = f2bf(v);
          } else if (col < 1536) {
            int c2 = col - 768; v += bias1[c2];
            int h = c2 >> 6, d = c2 & 63;
            k_buf[(((size_t)b * NH + h) * TT + t) * DH + d] = f2bf(v);
          } else {
            int c2 = col - 1536; v += bias2[c2];
            int h = c2 >> 6, d = c2 & 63;
            vt_buf[(((size_t)b * NH + h) * DH + d) * TT + t] = f2bf(v);   // V transposed
          }
        } else {
          out[(size_t)row * 768 + col] = v + bias0[col];
        }
      }
    }
  }
}

// ---------------- Attention (fused, R3 structure minus max-pass, plus swizzle) ----------------
// Block = 8 waves x 16 q-rows; wave w covers keys [w*256,(w+1)*256).
// Pass 1: QK^T -> e=exp2(s*cs) directly (no max subtraction; |s*cs|<~8 so f16-safe),
//         stash e packed f16 (32 VGPR), accumulate row-sums.
// Cross-wave sum via 1 LDS round-trip -> scale = gate/denom.
// Pass 2: P=e*scale -> LDS bf16 -> PV MFMA + coalesced nt A-write; LDS Z-reduce.
union AttnSM {
  u16  P[NW][16][136];   // bf16 gated P staging (34.8 KB)
  float Z[NW][16][72];   // cross-wave z reduce (36.9 KB)
};

__global__ __launch_bounds__(512, 4)
void k_attn(const u16* __restrict__ Q, const u16* __restrict__ Kb,
            const u16* __restrict__ Vt, const float* __restrict__ gates,
            float* __restrict__ A_out, u16* __restrict__ z_buf) {
  // XCD-bijective swizzle: 3072 blocks; XCD = flat%8; bh group pinned per XCD.
  int flat = blockIdx.x;
  int g = flat & 7, t = flat >> 3;            // t in 0..383
  int qg = t & 127, bh = (t >> 7) * 8 + g;    // bh in 0..23
  int b = bh / NH, h = bh % NH;
  int tid = threadIdx.x;
  int lane = tid & 63, w = tid >> 6;          // w in 0..7
  int ln = lane & 15, lg = lane >> 4;
  int q0 = qg * 16;
  const u16* Qbh = Q  + (size_t)bh * TT * DH;
  const u16* Kbh = Kb + (size_t)bh * TT * DH;
  const u16* Vbh = Vt + (size_t)bh * DH * TT;
  float gate = gates[bh];

  __shared__ float red_s[NW][16];
  __shared__ AttnSM sm;

  short8 qf0 = *(const short8*)&Qbh[(size_t)(q0 + ln) * DH + lg * 8];
  short8 qf1 = *(const short8*)&Qbh[(size_t)(q0 + ln) * DH + 32 + lg * 8];

  const float cs = 0.18033688011112042f;   // log2(e)/sqrt(64)
  int base = w * 256;

  // ---- pass 1: QK^T -> e (stash f16), row sums ----
  half2v sh[16][2];
  float l[4] = {0.f, 0.f, 0.f, 0.f};
  #pragma unroll
  for (int grp = 0; grp < 4; ++grp) {       // 64-key batches
    short8 kt[4][2];
    #pragma unroll
    for (int tt = 0; tt < 4; ++tt) {
      const u16* kp = &Kbh[(size_t)(base + grp * 64 + tt * 16 + ln) * DH + lg * 8];
      kt[tt][0] = *(const short8*)kp;
      kt[tt][1] = *(const short8*)(kp + 32);
    }
    __builtin_amdgcn_sched_barrier(0);      // pin: all 8 loads issued before compute
    #pragma unroll
    for (int tt = 0; tt < 4; ++tt) {
      f32x4 c = {0.f, 0.f, 0.f, 0.f};
      c = __builtin_amdgcn_mfma_f32_16x16x32_bf16(qf0, kt[tt][0], c, 0, 0, 0);
      c = __builtin_amdgcn_mfma_f32_16x16x32_bf16(qf1, kt[tt][1], c, 0, 0, 0);
      float e0 = __builtin_amdgcn_exp2f(c[0] * cs);
      float e1 = __builtin_amdgcn_exp2f(c[1] * cs);
      float e2 = __builtin_amdgcn_exp2f(c[2] * cs);
      float e3 = __builtin_amdgcn_exp2f(c[3] * cs);
      l[0] += e0; l[1] += e1; l[2] += e2; l[3] += e3;
      sh[grp * 4 + tt][0] = __builtin_amdgcn_cvt_pkrtz(e0, e1);
      sh[grp * 4 + tt][1] = __builtin_amdgcn_cvt_pkrtz(e2, e3);
    }
  }

  // ---- cross-lane + cross-wave row-sum -> scale ----
  #pragma unroll
  for (int r = 0; r < 4; ++r)
    #pragma unroll
    for (int mk = 1; mk <= 8; mk <<= 1) l[r] += __shfl_xor(l[r], mk, 64);
  if (ln == 0) {
    #pragma unroll
    for (int r = 0; r < 4; ++r) red_s[w][lg * 4 + r] = l[r];
  }
  __syncthreads();
  float scale[4];
  #pragma unroll
  for (int r = 0; r < 4; ++r) {
    int q = lg * 4 + r;
    float denom = red_s[0][q];
    #pragma unroll
    for (int i = 1; i < NW; ++i) denom += red_s[i][q];
    scale[r] = gate / denom;   // gate folded post-softmax
  }

  // ---- pass 2: per 128-key chunk: P->LDS (bf16), PV MFMA, coalesced nt A-write ----
  float* Arow = A_out + ((size_t)bh * TT + q0) * TT;
  f32x4 zacc[4] = {};
  #pragma unroll
  for (int ch = 0; ch < 2; ++ch) {
    #pragma unroll
    for (int tt = 0; tt < 8; ++tt) {
      int t16 = ch * 8 + tt;
      #pragma unroll
      for (int r = 0; r < 4; ++r) {
        float p = (float)sh[t16][r >> 1][r & 1] * scale[r];
        sm.P[w][lg * 4 + r][tt * 16 + ln] = f2bf(p);
      }
    }
    // PV over this 128-key chunk (wave-private LDS region)
    #pragma unroll
    for (int ks = 0; ks < 4; ++ks) {
      short8 pf = *(const short8*)&sm.P[w][ln][ks * 32 + lg * 8];
      short8 vt_[4];
      #pragma unroll
      for (int dt = 0; dt < 4; ++dt)
        vt_[dt] = *(const short8*)&Vbh[(size_t)(dt * 16 + ln) * TT + base + ch * 128 + ks * 32 + lg * 8];
      __builtin_amdgcn_sched_barrier(0);
      #pragma unroll
      for (int dt = 0; dt < 4; ++dt)
        zacc[dt] = __builtin_amdgcn_mfma_f32_16x16x32_bf16(pf, vt_[dt], zacc[dt], 0, 0, 0);
    }
    // coalesced nt A-write: 64 lanes x 8B = 512B contiguous per row
    #pragma unroll
    for (int row = 0; row < 16; ++row) {
      unsigned int pk = *(const unsigned int*)&sm.P[w][row][lane * 2];
      f32x2 v2;
      v2.x = bf2f((u16)pk);
      v2.y = bf2f((u16)(pk >> 16));
      __builtin_nontemporal_store(v2,
          (f32x2*)&Arow[(size_t)row * TT + base + ch * 128 + lane * 2]);
    }
  }

  // ---- cross-wave Z reduce (reuses P's LDS) ----
  __syncthreads();
  #pragma unroll
  for (int dt = 0; dt < 4; ++dt)
    #pragma unroll
    for (int r = 0; r < 4; ++r)
      sm.Z[w][lg * 4 + r][dt * 16 + ln] = zacc[dt][r];
  __syncthreads();
  {
    int d = lane;
    #pragma unroll
    for (int i = 0; i < 2; ++i) {
      int qq = w + i * 8;
      float s = 0.f;
      #pragma unroll
      for (int j = 0; j < NW; ++j) s += sm.Z[j][qq][d];
      z_buf[((size_t)b * TT + q0 + qq) * D_MODEL + h * DH + d] = f2bf(s);
    }
  }
}

extern "C" void kernel_launch(void* const* d_in, const int* in_sizes, int n_in,
                              void* d_out, int out_size, void* d_ws, size_t ws_size,
                              hipStream_t stream) {
  const float* x     = (const float*)d_in[0];
  const float* gates = (const float*)d_in[1];
  const float* Wq    = (const float*)d_in[2];
  const float* bq    = (const float*)d_in[3];
  const float* Wk    = (const float*)d_in[4];
  const float* bk    = (const float*)d_in[5];
  const float* Wv    = (const float*)d_in[6];
  const float* bv    = (const float*)d_in[7];
  const float* Wo    = (const float*)d_in[8];
  const float* bo    = (const float*)d_in[9];
  float* out   = (float*)d_out;
  float* A_out = out + (size_t)BT * D_MODEL;

  char* ws = (char*)d_ws;
  u16* x_bf   = (u16*)ws; ws += (size_t)BT * D_MODEL * 2;
  u16* wqkvT  = (u16*)ws; ws += (size_t)3 * D_MODEL * D_MODEL * 2;
  u16* woT    = (u16*)ws; ws += (size_t)D_MODEL * D_MODEL * 2;
  u16* q_buf  = (u16*)ws; ws += (size_t)BT * D_MODEL * 2;
  u16* k_buf  = (u16*)ws; ws += (size_t)BT * D_MODEL * 2;
  u16* vt_buf = (u16*)ws; ws += (size_t)BT * D_MODEL * 2;
  u16* z_buf  = (u16*)ws; ws += (size_t)BT * D_MODEL * 2;

  k_convert_x<<<(BT * D_MODEL / 4 + 255) / 256, 256, 0, stream>>>(x, x_bf, BT * D_MODEL / 4);
  dim3 tb(32, 8);
  dim3 tg(D_MODEL / 32, D_MODEL / 32);
  k_transpose_bf16<<<tg, tb, 0, stream>>>(Wq, wqkvT, D_MODEL, D_MODEL);
  k_transpose_bf16<<<tg, tb, 0, stream>>>(Wk, wqkvT + (size_t)D_MODEL * D_MODEL, D_MODEL, D_MODEL);
  k_transpose_bf16<<<tg, tb, 0, stream>>>(Wv, wqkvT + (size_t)2 * D_MODEL * D_MODEL, D_MODEL, D_MODEL);
  k_transpose_bf16<<<tg, tb, 0, stream>>>(Wo, woT, D_MODEL, D_MODEL);

  k_gemm<0><<<dim3(2304 / 128, BT / 128), 256, 0, stream>>>(
      x_bf, wqkvT, bq, bk, bv, q_buf, k_buf, vt_buf, nullptr, D_MODEL);

  k_attn<<<dim3(3072), 512, 0, stream>>>(q_buf, k_buf, vt_buf, gates, A_out, z_buf);

  k_gemm<1><<<dim3(D_MODEL / 128, BT / 128), 256, 0, stream>>>(
      z_buf, woT, bo, nullptr, nullptr, nullptr, nullptr, nullptr, out, D_MODEL);
}